// Round 8
// baseline (317.489 us; speedup 1.0000x reference)
//
#include <hip/hip_runtime.h>

// AdaptiveAttentionLoss: focal CE (C=2, beta=2) + segmented mean (G=4096).
// R7/R8 theory: floor is LDS-atomic lane-RMW throughput (33.5M lane-RMWs ~100us).
//   Evidence: R1 (VALU 55%) 111us vs R6 (VALU 10%, occ 70%) 143us - neither
//   VALU, HBM (13-17%), nor occupancy moves the floor.
// Fix: ONE packed ds_add_u64 per sample ((1<<46)+round(val*2^26)) instead of
//   two u32 atomics; atomic flush -> dense stores + reduce kernel.

#define G_GROUPS 4096
#define ACC_THREADS 1024
#define ACC_BLOCKS_MAX 512
#define VAL_MASK ((1ull << 46) - 1)
#define FP_SCALE 67108864.0          // 2^26
#define FP_INV   (1.0 / 67108864.0)

// ws layout (u64 units): [0,4096) acc_cnt | [4096,8192) acc_val | rows[nb][4096]

__global__ void aal_zero_kernel(unsigned long long* __restrict__ acc) {
    int i = blockIdx.x * blockDim.x + threadIdx.x;
    if (i < 2 * G_GROUPS) acc[i] = 0ull;
}

// ce = softplus(d), p = sigmoid(-d), w = 1-p^2, val = w*ce  (val >= 0).
// Pack: count=1 in bits [63:46], val fixed-point 2^-26 in bits [45:0].
// Worst case/block: 32768 samples one group -> cnt = 2^15 < 2^18,
// sum < 2^45 < 2^46 -> no field overflow.
__device__ __forceinline__ unsigned long long aal_pack(float xA, float xB, int lab) {
    float xt = lab ? xB : xA;
    float xo = lab ? xA : xB;
    float d  = xo - xt;
    float t  = __expf(-fabsf(d));        // v_exp_f32, t in (0,1]
    float denom = 1.0f + t;
    float ce = fmaxf(d, 0.0f) + __logf(denom);
    float r  = __builtin_amdgcn_rcpf(denom);
    float p  = (d >= 0.0f ? t : 1.0f) * r;
    float w  = fmaf(-p, p, 1.0f);        // 1 - p^2 (beta=2)
    double val = (double)(w * ce);       // f64 so val*2^26 is exact pre-round
    unsigned long long q = (unsigned long long)(val * FP_SCALE + 0.5);
    return (1ull << 46) + q;
}

// 32 KiB LDS (4096 x u64); 1024 thr; 2 blocks/CU -> 32 waves/CU.
__global__ __launch_bounds__(ACC_THREADS, 8) void aal_accum_kernel(
    const float4* __restrict__ x2,    // [N/2]: 2 samples per float4
    const int4*  __restrict__ idx4,   // [N/4]
    const int4*  __restrict__ lab4,   // [N/4]
    unsigned long long* __restrict__ rows,  // [nblocks][G]
    int nvec4)                        // N/4
{
    __shared__ unsigned long long s_hist[G_GROUPS];
    for (int i = threadIdx.x; i < G_GROUPS; i += ACC_THREADS) s_hist[i] = 0ull;
    __syncthreads();

    const int tid    = blockIdx.x * ACC_THREADS + threadIdx.x;
    const int stride = gridDim.x * ACC_THREADS;

    int v = tid;
    // 2 vec4-units (8 samples) per iteration; all loads 16B lane-contiguous.
    for (; v + stride < nvec4; v += 2 * stride) {
        float4 a0 = x2[2 * v];
        float4 b0 = x2[2 * v + 1];
        int4   i0 = idx4[v];
        int4   l0 = lab4[v];
        float4 a1 = x2[2 * (v + stride)];
        float4 b1 = x2[2 * (v + stride) + 1];
        int4   i1 = idx4[v + stride];
        int4   l1 = lab4[v + stride];

        atomicAdd(&s_hist[i0.x], aal_pack(a0.x, a0.y, l0.x));
        atomicAdd(&s_hist[i0.y], aal_pack(a0.z, a0.w, l0.y));
        atomicAdd(&s_hist[i0.z], aal_pack(b0.x, b0.y, l0.z));
        atomicAdd(&s_hist[i0.w], aal_pack(b0.z, b0.w, l0.w));
        atomicAdd(&s_hist[i1.x], aal_pack(a1.x, a1.y, l1.x));
        atomicAdd(&s_hist[i1.y], aal_pack(a1.z, a1.w, l1.y));
        atomicAdd(&s_hist[i1.z], aal_pack(b1.x, b1.y, l1.z));
        atomicAdd(&s_hist[i1.w], aal_pack(b1.z, b1.w, l1.w));
    }
    for (; v < nvec4; v += stride) {
        float4 a = x2[2 * v];
        float4 b = x2[2 * v + 1];
        int4   iv = idx4[v];
        int4   lv = lab4[v];
        atomicAdd(&s_hist[iv.x], aal_pack(a.x, a.y, lv.x));
        atomicAdd(&s_hist[iv.y], aal_pack(a.z, a.w, lv.y));
        atomicAdd(&s_hist[iv.z], aal_pack(b.x, b.y, lv.z));
        atomicAdd(&s_hist[iv.w], aal_pack(b.z, b.w, lv.w));
    }
    __syncthreads();

    // Dense non-atomic flush: 32KB/block, coalesced stores.
    size_t base = (size_t)blockIdx.x * G_GROUPS;
    for (int i = threadIdx.x; i < G_GROUPS; i += ACC_THREADS)
        rows[base + i] = s_hist[i];
}

// 64 blocks x 256 thr: (b&15) -> group chunk of 256, (b>>4) -> row chunk.
__global__ __launch_bounds__(256) void aal_reduce_kernel(
    const unsigned long long* __restrict__ rows,
    unsigned long long* __restrict__ acc_cnt,
    unsigned long long* __restrict__ acc_val,
    int nblocks)
{
    const int g     = (blockIdx.x & 15) * 256 + threadIdx.x;
    const int chunk = blockIdx.x >> 4;                 // 0..3
    const int rpc   = (nblocks + 3) >> 2;
    const int r0    = chunk * rpc;
    const int r1    = min(r0 + rpc, nblocks);
    unsigned long long c = 0ull, s = 0ull;
    for (int r = r0; r < r1; ++r) {
        unsigned long long p = rows[(size_t)r * G_GROUPS + g];
        c += p >> 46;          // unpack per-summand: overflow-safe
        s += p & VAL_MASK;
    }
    atomicAdd(&acc_cnt[g], c);
    atomicAdd(&acc_val[g], s);
}

__global__ __launch_bounds__(1024) void aal_final_kernel(
    const unsigned long long* __restrict__ acc_cnt,
    const unsigned long long* __restrict__ acc_val,
    float* __restrict__ out)
{
    __shared__ float s_m[1024];
    __shared__ float s_p[1024];
    const int t = threadIdx.x;
    float msum = 0.0f, pres = 0.0f;
    for (int g = t; g < G_GROUPS; g += 1024) {
        unsigned long long c = acc_cnt[g];
        if (c) {
            double mean = (double)acc_val[g] * FP_INV / (double)c;
            msum += (float)mean;
            pres += 1.0f;
        }
    }
    s_m[t] = msum;
    s_p[t] = pres;
    __syncthreads();
    for (int o = 512; o > 0; o >>= 1) {
        if (t < o) {
            s_m[t] += s_m[t + o];
            s_p[t] += s_p[t + o];
        }
        __syncthreads();
    }
    if (t == 0) out[0] = s_m[0] / s_p[0];
}

extern "C" void kernel_launch(void* const* d_in, const int* in_sizes, int n_in,
                              void* d_out, int out_size, void* d_ws, size_t ws_size,
                              hipStream_t stream) {
    const float4* x2   = (const float4*)d_in[0];
    const int4*   idx4 = (const int4*)d_in[1];
    const int4*   lab4 = (const int4*)d_in[2];
    const int N = in_sizes[1];          // N samples (2^24)
    const int nvec4 = N / 4;

    unsigned long long* acc  = (unsigned long long*)d_ws;   // cnt[G], val[G]
    unsigned long long* rows = acc + 2 * G_GROUPS;
    float* out = (float*)d_out;

    // Clamp block count to available scratch (rows need nb*32KB).
    size_t avail_u64 = ws_size / 8;
    int nblocks = ACC_BLOCKS_MAX;
    if (avail_u64 > 2 * G_GROUPS) {
        size_t cap = (avail_u64 - 2 * G_GROUPS) / G_GROUPS;
        if ((size_t)nblocks > cap) nblocks = (int)cap;
    } else {
        nblocks = 1;
    }
    if (nblocks < 1) nblocks = 1;

    aal_zero_kernel<<<(2 * G_GROUPS + 255) / 256, 256, 0, stream>>>(acc);
    aal_accum_kernel<<<nblocks, ACC_THREADS, 0, stream>>>(x2, idx4, lab4, rows, nvec4);
    aal_reduce_kernel<<<64, 256, 0, stream>>>(rows, acc, acc + G_GROUPS, nblocks);
    aal_final_kernel<<<1, 1024, 0, stream>>>(acc, acc + G_GROUPS, out);
}